// Round 5
// baseline (215.333 us; speedup 1.0000x reference)
//
#include <hip/hip_runtime.h>
#include <hip/hip_bf16.h>

// Leave-one-out Gaussian-kernel regression (Nadaraya-Watson), N=4096, D_IN=4, D_OUT=3.
// out[i,c] = (sum_{j!=i} K_jic * Y[j,c]) / (sum_{j!=i} K_jic)
//
// R5 = MEASUREMENT ROUND, 16x variant (R3/R4 2x probe never ran -- two GPU
// acquisition timeouts; redesigned so a SINGLE successful bench resolves the
// kernel-share question unambiguously).
// Real path = R1 best config (TI=4, BLK=256, 75.44us), untouched. Probe =
// REP=15 extra full j-sweeps with asm-opaqued index jj (no CSE/hoist) into
// dummy accumulators kept live via asm sinks (rule #17). Outcomes:
//   * kernel ~36us throughput-bound  -> dur ~600us
//   * kernel ~3-6us (harness floor: 39.4us poison fill + dozens of tiny
//     reset dispatches dominate the timed graph) -> dur ~120-160us
//   * either way kde_fused finally TOPS the rocprof table -> direct
//     VALUBusy/Occupancy/FETCH counters, and (dur-75.4)/15 = true kernel us.

constexpr int BLK = 256;  // threads per block (4 waves)
constexpr int TI  = 4;    // query points per block
constexpr int REP = 15;   // probe work multiplier (total work = 1 real + 15 probe)

__global__ __launch_bounds__(BLK) void kde_fused(const float* __restrict__ x,
                                                 const float* __restrict__ tX,
                                                 const float* __restrict__ Y,
                                                 const float* __restrict__ W,
                                                 const float* __restrict__ hptr,
                                                 float* __restrict__ out, int N) {
    const int i0  = blockIdx.x * TI;
    const int tid = threadIdx.x;

    const float h = hptr[0];
    const float scale = -0.72134752044448170368f / (h * h);  // -log2(e)/(2h^2)
    const float m2s   = -2.f * scale;

    float w[12];
#pragma unroll
    for (int k = 0; k < 12; ++k) w[k] = W[k];

    float w2[TI][3];
#pragma unroll
    for (int a = 0; a < TI; ++a) {
        float4 xv = ((const float4*)x)[i0 + a];
#pragma unroll
        for (int c = 0; c < 3; ++c) {
            float fx = fmaf(xv.x, w[4 * c + 0],
                       fmaf(xv.y, w[4 * c + 1],
                       fmaf(xv.z, w[4 * c + 2], xv.w * w[4 * c + 3])));
            w2[a][c] = m2s * fx;
        }
    }

    float num[TI][3], den[TI][3];
#pragma unroll
    for (int a = 0; a < TI; ++a)
#pragma unroll
        for (int c = 0; c < 3; ++c) { num[a][c] = 0.f; den[a][c] = 0.f; }

    // ---- real pass (identical to R1) ----
#pragma unroll 2
    for (int j = tid; j < N; j += BLK) {
        float4 tv = ((const float4*)tX)[j];
        float yv[3];
        yv[0] = Y[3 * j + 0]; yv[1] = Y[3 * j + 1]; yv[2] = Y[3 * j + 2];
        float ft[3], A[3];
#pragma unroll
        for (int c = 0; c < 3; ++c) {
            ft[c] = fmaf(tv.x, w[4 * c + 0],
                    fmaf(tv.y, w[4 * c + 1],
                    fmaf(tv.z, w[4 * c + 2], tv.w * w[4 * c + 3])));
            float v = scale * ft[c];
            A[c] = v * ft[c];
        }
#pragma unroll
        for (int a = 0; a < TI; ++a)
#pragma unroll
            for (int c = 0; c < 3; ++c) {
                float arg = fmaf(w2[a][c], ft[c], A[c]);
                float k   = __builtin_amdgcn_exp2f(arg);
                den[a][c] += k;
                num[a][c]  = fmaf(k, yv[c], num[a][c]);
            }
    }

    // ---- probe passes: REP full j-sweeps, opaqued index, dummy accumulators ----
    float num2[TI][3], den2[TI][3];
#pragma unroll
    for (int a = 0; a < TI; ++a)
#pragma unroll
        for (int c = 0; c < 3; ++c) { num2[a][c] = 0.f; den2[a][c] = 0.f; }

    for (int r = 0; r < REP; ++r) {
        for (int j = tid; j < N; j += BLK) {
            int jj = j;
            asm volatile("" : "+v"(jj));  // opaque index: loads/evals can't CSE or hoist
            float4 tv = ((const float4*)tX)[jj];
            float yv[3];
            yv[0] = Y[3 * jj + 0]; yv[1] = Y[3 * jj + 1]; yv[2] = Y[3 * jj + 2];
            float ft[3], A[3];
#pragma unroll
            for (int c = 0; c < 3; ++c) {
                ft[c] = fmaf(tv.x, w[4 * c + 0],
                        fmaf(tv.y, w[4 * c + 1],
                        fmaf(tv.z, w[4 * c + 2], tv.w * w[4 * c + 3])));
                float v = scale * ft[c];
                A[c] = v * ft[c];
            }
#pragma unroll
            for (int a = 0; a < TI; ++a)
#pragma unroll
                for (int c = 0; c < 3; ++c) {
                    float arg = fmaf(w2[a][c], ft[c], A[c]);
                    float k   = __builtin_amdgcn_exp2f(arg);
                    den2[a][c] += k;
                    num2[a][c]  = fmaf(k, yv[c], num2[a][c]);
                }
        }
    }
    // Keep probe accumulators live without affecting output (rule-#17 sink).
#pragma unroll
    for (int a = 0; a < TI; ++a)
#pragma unroll
        for (int c = 0; c < 3; ++c)
            asm volatile("" :: "v"(num2[a][c]), "v"(den2[a][c]));

    // 64-lane wave butterfly, then 4-wave LDS combine (unchanged)
    __shared__ float s_n[4][TI * 3];
    __shared__ float s_d[4][TI * 3];
    const int lane = tid & 63, wave = tid >> 6;
#pragma unroll
    for (int a = 0; a < TI; ++a)
#pragma unroll
        for (int c = 0; c < 3; ++c) {
            float n_ = num[a][c], d_ = den[a][c];
#pragma unroll
            for (int off = 32; off > 0; off >>= 1) {
                n_ += __shfl_down(n_, off, 64);
                d_ += __shfl_down(d_, off, 64);
            }
            if (lane == 0) { s_n[wave][a * 3 + c] = n_; s_d[wave][a * 3 + c] = d_; }
        }
    __syncthreads();

    if (tid < TI * 3) {
        const int a = tid / 3, c = tid - 3 * a;
        const int i = i0 + a;
        float n_ = s_n[0][tid] + s_n[1][tid] + s_n[2][tid] + s_n[3][tid];
        float d_ = s_d[0][tid] + s_d[1][tid] + s_d[2][tid] + s_d[3][tid];

        // Self-term (j==i), recomputed from globals with the SAME op order as
        // the main loop. Runtime c indexes GLOBAL W (VMEM), not a reg array.
        float4 xv = ((const float4*)x)[i];
        float fx = fmaf(xv.x, W[4 * c + 0],
                   fmaf(xv.y, W[4 * c + 1],
                   fmaf(xv.z, W[4 * c + 2], xv.w * W[4 * c + 3])));
        float w2v = m2s * fx;
        float4 tv = ((const float4*)tX)[i];
        float ft = fmaf(tv.x, W[4 * c + 0],
                   fmaf(tv.y, W[4 * c + 1],
                   fmaf(tv.z, W[4 * c + 2], tv.w * W[4 * c + 3])));
        float v  = scale * ft;
        float A  = v * ft;
        float kii = __builtin_amdgcn_exp2f(fmaf(w2v, ft, A));
        float yii = Y[3 * i + c];

        out[3 * i + c] = (n_ - kii * yii) / (d_ - kii);
    }
}

extern "C" void kernel_launch(void* const* d_in, const int* in_sizes, int n_in,
                              void* d_out, int out_size, void* d_ws, size_t ws_size,
                              hipStream_t stream) {
    const float* x  = (const float*)d_in[0];  // [N,4]
    const float* tX = (const float*)d_in[1];  // [N,4]
    const float* Y  = (const float*)d_in[2];  // [N,3]
    const float* W  = (const float*)d_in[3];  // [3,4]
    const float* h  = (const float*)d_in[4];  // [1]

    const int N = in_sizes[0] / 4;  // 4096

    kde_fused<<<N / TI, BLK, 0, stream>>>(x, tX, Y, W, h, (float*)d_out, N);
}

// Round 6
// 74.939 us; speedup vs baseline: 2.8734x; 2.8734x over previous
//
#include <hip/hip_runtime.h>
#include <hip/hip_bf16.h>

// Leave-one-out Gaussian-kernel regression (Nadaraya-Watson), N=4096, D_IN=4, D_OUT=3.
// out[i,c] = (sum_{j!=i} K_jic * Y[j,c]) / (sum_{j!=i} K_jic)
// K_jic = exp(-0.5*((Ft[j,c]-Fx[i,c])/h)^2),  Fx = x@W^T, Ft = train_X@W^T.
//
// Algebra: with s = -log2(e)/(2h^2):  K' = 2^{ fma(w2, ft, A) },
//   A = (s*ft)*ft (per j),  w2 = -2s*fx (per i);  the 2^{s*fx^2} factor
//   cancels in num/den. Inner eval = 1 fma + 1 exp2 + 2 acc ops.
//
// R6 (ILP for the trans pipe). R5's 16x probe measured the true kernel:
// ~11.5us/pass, VALUBusy 84%, FETCH 626KB (L2-resident), VGPR 40, no
// conflicts -> pure VALU/trans throughput-bound. Busy-cycle model says
// v_exp_f32 ~16cyc/wave64 dominates (~55-60% of busy); pipe-overlap bound is
// ~5-6us but we sit at 11.5 -> trans pipe ~45% idle from intra-wave
// dependence (unroll 2 = only 24 independent exp chains). This round:
// unroll 4 + batched phases (args[12] -> exp2[12] -> accumulates) = 48
// independent chains per wave to keep the trans unit fed. VGPR headroom is
// huge (40 -> ~80 still 5 waves/SIMD).
// Harness context: dur_us ~= ~64us fixed fills/dispatches + kernel; predicted
// kernel 11.5 -> 8-9 => dur ~72-73. If unchanged: kernel is at its pipe wall
// (practical roofline; kernel is <15% of graded time).

constexpr int BLK = 256;  // threads per block (4 waves)
constexpr int TI  = 4;    // query points per block

__global__ __launch_bounds__(BLK) void kde_fused(const float* __restrict__ x,
                                                 const float* __restrict__ tX,
                                                 const float* __restrict__ Y,
                                                 const float* __restrict__ W,
                                                 const float* __restrict__ hptr,
                                                 float* __restrict__ out, int N) {
    const int i0  = blockIdx.x * TI;
    const int tid = threadIdx.x;

    const float h = hptr[0];
    const float scale = -0.72134752044448170368f / (h * h);  // -log2(e)/(2h^2)
    const float m2s   = -2.f * scale;

    // W is 12 wave-uniform floats -> scalar loads
    float w[12];
#pragma unroll
    for (int k = 0; k < 12; ++k) w[k] = W[k];

    // Per-query constants w2[a][c] = -2*scale*fx  (all static indexing)
    float w2[TI][3];
#pragma unroll
    for (int a = 0; a < TI; ++a) {
        float4 xv = ((const float4*)x)[i0 + a];
#pragma unroll
        for (int c = 0; c < 3; ++c) {
            float fx = fmaf(xv.x, w[4 * c + 0],
                       fmaf(xv.y, w[4 * c + 1],
                       fmaf(xv.z, w[4 * c + 2], xv.w * w[4 * c + 3])));
            w2[a][c] = m2s * fx;
        }
    }

    float num[TI][3], den[TI][3];
#pragma unroll
    for (int a = 0; a < TI; ++a)
#pragma unroll
        for (int c = 0; c < 3; ++c) { num[a][c] = 0.f; den[a][c] = 0.f; }

#pragma unroll 4
    for (int j = tid; j < N; j += BLK) {
        float4 tv = ((const float4*)tX)[j];
        float yv[3];
        yv[0] = Y[3 * j + 0]; yv[1] = Y[3 * j + 1]; yv[2] = Y[3 * j + 2];
        float ft[3], A[3];
#pragma unroll
        for (int c = 0; c < 3; ++c) {
            ft[c] = fmaf(tv.x, w[4 * c + 0],
                    fmaf(tv.y, w[4 * c + 1],
                    fmaf(tv.z, w[4 * c + 2], tv.w * w[4 * c + 3])));
            float v = scale * ft[c];
            A[c] = v * ft[c];
        }
        // Phase 1: all 12 args (independent fmas)
        float arg[TI][3];
#pragma unroll
        for (int a = 0; a < TI; ++a)
#pragma unroll
            for (int c = 0; c < 3; ++c)
                arg[a][c] = fmaf(w2[a][c], ft[c], A[c]);
        // Phase 2: all 12 exp2s (independent trans ops -- keep the pipe fed)
        float kk[TI][3];
#pragma unroll
        for (int a = 0; a < TI; ++a)
#pragma unroll
            for (int c = 0; c < 3; ++c)
                kk[a][c] = __builtin_amdgcn_exp2f(arg[a][c]);
        // Phase 3: accumulates
#pragma unroll
        for (int a = 0; a < TI; ++a)
#pragma unroll
            for (int c = 0; c < 3; ++c) {
                den[a][c] += kk[a][c];
                num[a][c]  = fmaf(kk[a][c], yv[c], num[a][c]);
            }
    }

    // 64-lane wave butterfly, then 4-wave LDS combine
    __shared__ float s_n[4][TI * 3];
    __shared__ float s_d[4][TI * 3];
    const int lane = tid & 63, wave = tid >> 6;
#pragma unroll
    for (int a = 0; a < TI; ++a)
#pragma unroll
        for (int c = 0; c < 3; ++c) {
            float n_ = num[a][c], d_ = den[a][c];
#pragma unroll
            for (int off = 32; off > 0; off >>= 1) {
                n_ += __shfl_down(n_, off, 64);
                d_ += __shfl_down(d_, off, 64);
            }
            if (lane == 0) { s_n[wave][a * 3 + c] = n_; s_d[wave][a * 3 + c] = d_; }
        }
    __syncthreads();

    if (tid < TI * 3) {
        const int a = tid / 3, c = tid - 3 * a;
        const int i = i0 + a;
        float n_ = s_n[0][tid] + s_n[1][tid] + s_n[2][tid] + s_n[3][tid];
        float d_ = s_d[0][tid] + s_d[1][tid] + s_d[2][tid] + s_d[3][tid];

        // Self-term (j==i), recomputed from globals with the SAME op order as
        // the main loop. Runtime c indexes GLOBAL W (VMEM), not a reg array.
        float4 xv = ((const float4*)x)[i];
        float fx = fmaf(xv.x, W[4 * c + 0],
                   fmaf(xv.y, W[4 * c + 1],
                   fmaf(xv.z, W[4 * c + 2], xv.w * W[4 * c + 3])));
        float w2v = m2s * fx;
        float4 tv = ((const float4*)tX)[i];
        float ft = fmaf(tv.x, W[4 * c + 0],
                   fmaf(tv.y, W[4 * c + 1],
                   fmaf(tv.z, W[4 * c + 2], tv.w * W[4 * c + 3])));
        float v  = scale * ft;
        float A  = v * ft;
        float kii = __builtin_amdgcn_exp2f(fmaf(w2v, ft, A));
        float yii = Y[3 * i + c];

        out[3 * i + c] = (n_ - kii * yii) / (d_ - kii);
    }
}

extern "C" void kernel_launch(void* const* d_in, const int* in_sizes, int n_in,
                              void* d_out, int out_size, void* d_ws, size_t ws_size,
                              hipStream_t stream) {
    const float* x  = (const float*)d_in[0];  // [N,4]
    const float* tX = (const float*)d_in[1];  // [N,4]
    const float* Y  = (const float*)d_in[2];  // [N,3]
    const float* W  = (const float*)d_in[3];  // [3,4]
    const float* h  = (const float*)d_in[4];  // [1]

    const int N = in_sizes[0] / 4;  // 4096

    kde_fused<<<N / TI, BLK, 0, stream>>>(x, tX, Y, W, h, (float*)d_out, N);
}